// Round 8
// baseline (1739.930 us; speedup 1.0000x reference)
//
#include <hip/hip_runtime.h>

#define Bb 4
#define Ss 1024
#define Dd 1024
#define Hh 16
#define HDd 64
#define FFf 2048
#define HIDh 4096
#define NTOK (Bb*Ss)
#define QKVN 3072

typedef unsigned short ush;
typedef short v8s __attribute__((ext_vector_type(8)));
typedef float v4f __attribute__((ext_vector_type(4)));

__device__ __forceinline__ float gelu_f(float x) {
  return 0.5f * x * (1.0f + erff(x * 0.70710678118654752f));
}
__device__ __forceinline__ ush f2bf(float x) {              // RNE
  unsigned int u = __float_as_uint(x);
  u += 0x7FFFu + ((u >> 16) & 1u);
  return (ush)(u >> 16);
}
__device__ __forceinline__ ush f2bf_t(float x) {            // truncate
  return (ush)(__float_as_uint(x) >> 16);
}
__device__ __forceinline__ float bf2f(ush h) {
  return __uint_as_float(((unsigned int)h) << 16);
}
__device__ __forceinline__ void gload16(const void* g, void* l) {
  __builtin_amdgcn_global_load_lds(
      (const __attribute__((address_space(1))) unsigned int*)g,
      (__attribute__((address_space(3))) unsigned int*)l, 16, 0, 0);
}

// ---------------- encoder GEMM: pre-split bf16x6, all-DMA -------------------
// A and B are both pre-split h/m/l ush planes ([rows][K]); all staging via
// global_load_lds (no f32 load, no in-loop conversion). Single-buffered:
// BN=128 -> 48KB LDS (QKV: 768 blocks, W1: 512); BN=64 -> 36KB (Wo/W2: 512
// blocks, >=2 blocks/CU). Fixed 6-product MFMA order = bit-identical to the
// old in-loop-converting gemm6_k.
// OUT=0: f32 C (optional GELU). OUT=1: gelu + h/m/l split C planes (W1 ->
// feeds W2's A directly; epilogue split == consumer-side split, bit-identical).
template<int GELU, int OUT, int BN>
__global__ __launch_bounds__(256)
void gemm6p_k(const ush* __restrict__ Ah, const ush* __restrict__ Am,
              const ush* __restrict__ Al, const ush* __restrict__ Bh,
              const ush* __restrict__ Bm, const ush* __restrict__ Bl,
              const float* __restrict__ bias, void* C0v, void* C1v, void* C2v,
              int M, int N, int K)
{
  constexpr int NI = BN / 32;
  __shared__ __align__(16) ush As0[128 * 32];
  __shared__ __align__(16) ush As1[128 * 32];
  __shared__ __align__(16) ush As2[128 * 32];
  __shared__ __align__(16) ush Bs0[BN * 32];
  __shared__ __align__(16) ush Bs1[BN * 32];
  __shared__ __align__(16) ush Bs2[BN * 32];
  const int tid = threadIdx.x;
  const int lane = tid & 63, wave = tid >> 6;
  const int bm = blockIdx.y * 128, bn = blockIdx.x * BN;
  const int wm = (wave & 1) * 64, wn = (wave >> 1) * (BN / 2);

  v4f acc[4][NI] = {};

  const int ks = (lane & 3) * 8;
  const int ra = wave * 32 + (lane >> 2);           // A staged row
  const ush* gAh = Ah + (size_t)(bm + ra) * K + ks;
  const ush* gAm = Am + (size_t)(bm + ra) * K + ks;
  const ush* gAl = Al + (size_t)(bm + ra) * K + ks;
  const int rb = (BN == 128) ? (wave * 32 + (lane >> 2)) : (wave * 16 + (lane >> 2));
  const ush* gBh = Bh + (size_t)(bn + rb) * K + ks;
  const ush* gBm = Bm + (size_t)(bn + rb) * K + ks;
  const ush* gBl = Bl + (size_t)(bn + rb) * K + ks;
  const size_t row16 = (size_t)16 * K;
  const int loa = wave * 1024;
  const int lob = (BN == 128) ? (wave * 1024) : (wave * 512);

  const int fr = lane & 15;
  const int fq = (lane >> 4) * 8;

  for (int k0 = 0; k0 < K; k0 += 32) {
    gload16(gAh + k0, &As0[loa]); gload16(gAh + row16 + k0, &As0[loa + 512]);
    gload16(gAm + k0, &As1[loa]); gload16(gAm + row16 + k0, &As1[loa + 512]);
    gload16(gAl + k0, &As2[loa]); gload16(gAl + row16 + k0, &As2[loa + 512]);
    gload16(gBh + k0, &Bs0[lob]);
    gload16(gBm + k0, &Bs1[lob]);
    gload16(gBl + k0, &Bs2[lob]);
    if (BN == 128) {
      gload16(gBh + row16 + k0, &Bs0[lob + 512]);
      gload16(gBm + row16 + k0, &Bs1[lob + 512]);
      gload16(gBl + row16 + k0, &Bs2[lob + 512]);
    }
    __syncthreads();
    v8s ah[4], am[4], al[4];
#pragma unroll
    for (int mi = 0; mi < 4; ++mi) {
      const int o = (wm + mi * 16 + fr) * 32 + fq;
      ah[mi] = *(const v8s*)&As0[o];
      am[mi] = *(const v8s*)&As1[o];
      al[mi] = *(const v8s*)&As2[o];
    }
#pragma unroll
    for (int ni = 0; ni < NI; ++ni) {
      const int o = (wn + ni * 16 + fr) * 32 + fq;
      v8s bh = *(const v8s*)&Bs0[o];
      v8s bm_ = *(const v8s*)&Bs1[o];
      v8s bl = *(const v8s*)&Bs2[o];
#pragma unroll
      for (int mi = 0; mi < 4; ++mi) {
        acc[mi][ni] = __builtin_amdgcn_mfma_f32_16x16x32_bf16(ah[mi], bh,  acc[mi][ni], 0, 0, 0);
        acc[mi][ni] = __builtin_amdgcn_mfma_f32_16x16x32_bf16(ah[mi], bm_, acc[mi][ni], 0, 0, 0);
        acc[mi][ni] = __builtin_amdgcn_mfma_f32_16x16x32_bf16(am[mi], bh,  acc[mi][ni], 0, 0, 0);
        acc[mi][ni] = __builtin_amdgcn_mfma_f32_16x16x32_bf16(ah[mi], bl,  acc[mi][ni], 0, 0, 0);
        acc[mi][ni] = __builtin_amdgcn_mfma_f32_16x16x32_bf16(al[mi], bh,  acc[mi][ni], 0, 0, 0);
        acc[mi][ni] = __builtin_amdgcn_mfma_f32_16x16x32_bf16(am[mi], bm_, acc[mi][ni], 0, 0, 0);
      }
    }
    __syncthreads();
  }
  const int eq = (lane >> 4) * 4;
#pragma unroll
  for (int ni = 0; ni < NI; ++ni) {
    const int col = bn + wn + ni * 16 + fr;
    const float bv = bias[col];
#pragma unroll
    for (int mi = 0; mi < 4; ++mi) {
      const int row0 = bm + wm + mi * 16 + eq;
#pragma unroll
      for (int r = 0; r < 4; ++r) {
        float v = acc[mi][ni][r] + bv;
        if (GELU) v = gelu_f(v);
        const size_t ix = (size_t)(row0 + r) * N + col;
        if (OUT == 0) {
          ((float*)C0v)[ix] = v;
        } else {
          ush ch = f2bf(v);
          float rr = v - bf2f(ch);
          ush cm = f2bf_t(rr);
          ush cl = f2bf_t(rr - bf2f(cm));
          ((ush*)C0v)[ix] = ch;
          ((ush*)C1v)[ix] = cm;
          ((ush*)C2v)[ix] = cl;
        }
      }
    }
  }
}

// ---------------- projector GEMM (R4-proven): 128x128, dbuf, nact skip ------
// A/B pre-split bf16 h/l planes, all-DMA staging, double-buffered LDS with
// prefetch-before-compute. 2D grid (mapping reverted to R4: compaction
// experiment R7 raised FETCH 135->360MB and regressed; R4 runs at the
// m97-structure ceiling ~876 TF).
// MODE 0: f32 out (P2). MODE 1: gelu + split bf16 h/l out planes (P1).
template<int MODE>
__global__ __launch_bounds__(256)
void gemm3p_k(const ush* __restrict__ Ah, const ush* __restrict__ Al,
              const ush* __restrict__ Bh, const ush* __restrict__ Bl,
              const float* __restrict__ bias, void* C0v, void* C1v,
              int M, int N, int K,
              const int* __restrict__ nact, const float* __restrict__ cvec)
{
  const int tid = threadIdx.x;
  const int bm = blockIdx.y * 128, bn = blockIdx.x * 128;
  if ((bm & (Ss - 1)) >= nact[bm >> 10]) {
    const int col = bn + (tid & 31) * 4;
    float4 cv = *(const float4*)&cvec[col];
    if (MODE == 0) {
      float* C = (float*)C0v;
#pragma unroll
      for (int i = 0; i < 16; ++i) {
        int row = bm + (tid >> 5) + i * 8;
        *(float4*)&C[(size_t)row * N + col] = cv;
      }
    } else {
      ush* Ch = (ush*)C0v; ush* Cl = (ush*)C1v;
      ushort4 hv, lv;
      hv.x = f2bf(cv.x); lv.x = f2bf(cv.x - bf2f(hv.x));
      hv.y = f2bf(cv.y); lv.y = f2bf(cv.y - bf2f(hv.y));
      hv.z = f2bf(cv.z); lv.z = f2bf(cv.z - bf2f(hv.z));
      hv.w = f2bf(cv.w); lv.w = f2bf(cv.w - bf2f(hv.w));
#pragma unroll
      for (int i = 0; i < 16; ++i) {
        int row = bm + (tid >> 5) + i * 8;
        *(ushort4*)&Ch[(size_t)row * N + col] = hv;
        *(ushort4*)&Cl[(size_t)row * N + col] = lv;
      }
    }
    return;
  }
  __shared__ __align__(16) ush As0[2][128 * 32];
  __shared__ __align__(16) ush As1[2][128 * 32];
  __shared__ __align__(16) ush Bs0[2][128 * 32];
  __shared__ __align__(16) ush Bs1[2][128 * 32];
  const int lane = tid & 63, wave = tid >> 6;
  const int wm = (wave & 1) * 64, wn = (wave >> 1) * 64;

  v4f acc[4][4] = {};

  const int rs = wave * 32 + (lane >> 2);
  const int ks = (lane & 3) * 8;
  const ush* gAh = Ah + (size_t)(bm + rs) * K + ks;
  const ush* gAl = Al + (size_t)(bm + rs) * K + ks;
  const ush* gBh = Bh + (size_t)(bn + rs) * K + ks;
  const ush* gBl = Bl + (size_t)(bn + rs) * K + ks;
  const size_t row16 = (size_t)16 * K;
  const int lbo0 = wave * 1024;
  const int lbo1 = wave * 1024 + 512;

  const int fr = lane & 15;
  const int fq = (lane >> 4) * 8;
  const int nt = K / 32;

  gload16(gAh, &As0[0][lbo0]); gload16(gAh + row16, &As0[0][lbo1]);
  gload16(gAl, &As1[0][lbo0]); gload16(gAl + row16, &As1[0][lbo1]);
  gload16(gBh, &Bs0[0][lbo0]); gload16(gBh + row16, &Bs0[0][lbo1]);
  gload16(gBl, &Bs1[0][lbo0]); gload16(gBl + row16, &Bs1[0][lbo1]);

  for (int t = 0; t < nt; ++t) {
    __syncthreads();
    const int cur = t & 1;
    if (t + 1 < nt) {
      const int nxt = cur ^ 1;
      const int k1 = (t + 1) * 32;
      gload16(gAh + k1, &As0[nxt][lbo0]); gload16(gAh + row16 + k1, &As0[nxt][lbo1]);
      gload16(gAl + k1, &As1[nxt][lbo0]); gload16(gAl + row16 + k1, &As1[nxt][lbo1]);
      gload16(gBh + k1, &Bs0[nxt][lbo0]); gload16(gBh + row16 + k1, &Bs0[nxt][lbo1]);
      gload16(gBl + k1, &Bs1[nxt][lbo0]); gload16(gBl + row16 + k1, &Bs1[nxt][lbo1]);
    }
    v8s afh[4], afl[4];
#pragma unroll
    for (int mi = 0; mi < 4; ++mi) {
      const int o = (wm + mi * 16 + fr) * 32 + fq;
      afh[mi] = *(const v8s*)&As0[cur][o];
      afl[mi] = *(const v8s*)&As1[cur][o];
    }
#pragma unroll
    for (int ni = 0; ni < 4; ++ni) {
      const int o = (wn + ni * 16 + fr) * 32 + fq;
      v8s bh = *(const v8s*)&Bs0[cur][o];
      v8s bl = *(const v8s*)&Bs1[cur][o];
#pragma unroll
      for (int mi = 0; mi < 4; ++mi) {
        acc[mi][ni] = __builtin_amdgcn_mfma_f32_16x16x32_bf16(afh[mi], bh, acc[mi][ni], 0, 0, 0);
        acc[mi][ni] = __builtin_amdgcn_mfma_f32_16x16x32_bf16(afh[mi], bl, acc[mi][ni], 0, 0, 0);
        acc[mi][ni] = __builtin_amdgcn_mfma_f32_16x16x32_bf16(afl[mi], bh, acc[mi][ni], 0, 0, 0);
      }
    }
  }
  const int eq = (lane >> 4) * 4;
#pragma unroll
  for (int ni = 0; ni < 4; ++ni) {
    const int col = bn + wn + ni * 16 + fr;
    const float bv = bias[col];
#pragma unroll
    for (int mi = 0; mi < 4; ++mi) {
      const int row0 = bm + wm + mi * 16 + eq;
#pragma unroll
      for (int r = 0; r < 4; ++r) {
        float v = acc[mi][ni][r] + bv;
        if (MODE == 0) {
          ((float*)C0v)[(size_t)(row0 + r) * N + col] = v;
        } else {
          v = gelu_f(v);
          ush h = f2bf(v);
          ush l = f2bf(v - bf2f(h));
          ((ush*)C0v)[(size_t)(row0 + r) * N + col] = h;
          ((ush*)C1v)[(size_t)(row0 + r) * N + col] = l;
        }
      }
    }
  }
}

// ---------------- f32 -> bf16 h/l row split (pooled pre-split) --------------
__global__ __launch_bounds__(256)
void psplit_k(const float* __restrict__ X, ush* __restrict__ H,
              ush* __restrict__ L)
{
  const size_t i = (size_t)blockIdx.x * 1024 + threadIdx.x * 4;
  float4 v = *(const float4*)&X[i];
  ushort4 h, l;
  h.x = f2bf(v.x); l.x = f2bf(v.x - bf2f(h.x));
  h.y = f2bf(v.y); l.y = f2bf(v.y - bf2f(h.y));
  h.z = f2bf(v.z); l.z = f2bf(v.z - bf2f(h.z));
  h.w = f2bf(v.w); l.w = f2bf(v.w - bf2f(h.w));
  *(ushort4*)&H[i] = h;
  *(ushort4*)&L[i] = l;
}

// ---------------- f32 -> bf16 h/m/l split (pass-1 x pre-split) --------------
__global__ __launch_bounds__(256)
void psplit3_k(const float* __restrict__ X, ush* __restrict__ H,
               ush* __restrict__ M, ush* __restrict__ L)
{
  const size_t i = (size_t)blockIdx.x * 1024 + threadIdx.x * 4;
  float4 v = *(const float4*)&X[i];
  ushort4 h, m, l;
  float r;
  h.x = f2bf(v.x); r = v.x - bf2f(h.x); m.x = f2bf_t(r); l.x = f2bf_t(r - bf2f(m.x));
  h.y = f2bf(v.y); r = v.y - bf2f(h.y); m.y = f2bf_t(r); l.y = f2bf_t(r - bf2f(m.y));
  h.z = f2bf(v.z); r = v.z - bf2f(h.z); m.z = f2bf_t(r); l.z = f2bf_t(r - bf2f(m.z));
  h.w = f2bf(v.w); r = v.w - bf2f(h.w); m.w = f2bf_t(r); l.w = f2bf_t(r - bf2f(m.w));
  *(ushort4*)&H[i] = h;
  *(ushort4*)&M[i] = m;
  *(ushort4*)&L[i] = l;
}

// ---------------- weight transpose + split kernels --------------------------
__global__ __launch_bounds__(256)
void wt_k(const float* __restrict__ W, ush* __restrict__ Th, ush* __restrict__ Tl,
          int K, int N)
{
  __shared__ float tile[32][33];
  const int k0 = blockIdx.y * 32, n0 = blockIdx.x * 32;
  const int tx = threadIdx.x & 31, ty = threadIdx.x >> 5;
#pragma unroll
  for (int j = 0; j < 32; j += 8)
    tile[ty + j][tx] = W[(size_t)(k0 + ty + j) * N + n0 + tx];
  __syncthreads();
#pragma unroll
  for (int j = 0; j < 32; j += 8) {
    float v = tile[tx][ty + j];
    ush h = f2bf(v);
    ush l = f2bf(v - bf2f(h));
    size_t o = (size_t)(n0 + ty + j) * K + k0 + tx;
    Th[o] = h;
    Tl[o] = l;
  }
}

__global__ __launch_bounds__(256)
void wt3_k(const float* __restrict__ W, ush* __restrict__ Th,
           ush* __restrict__ Tm, ush* __restrict__ Tl, int K, int N)
{
  __shared__ float tile[32][33];
  const int k0 = blockIdx.y * 32, n0 = blockIdx.x * 32;
  const int tx = threadIdx.x & 31, ty = threadIdx.x >> 5;
#pragma unroll
  for (int j = 0; j < 32; j += 8)
    tile[ty + j][tx] = W[(size_t)(k0 + ty + j) * N + n0 + tx];
  __syncthreads();
#pragma unroll
  for (int j = 0; j < 32; j += 8) {
    float v = tile[tx][ty + j];
    ush h = f2bf(v);
    float r = v - bf2f(h);
    ush m = f2bf_t(r);
    ush l = f2bf_t(r - bf2f(m));
    size_t o = (size_t)(n0 + ty + j) * K + k0 + tx;
    Th[o] = h;
    Tm[o] = m;
    Tl[o] = l;
  }
}

// ---------------- fused flash attention (bf16x2-split MFMA) -----------------
// Output written directly as h/m/l bf16 planes (feeds Wo's gemm6p A operand).
// Split in epilogue == split that the consumer GEMM used to do in-loop.
__device__ __forceinline__ int swz(int r, int c) {
  return (r << 6) + (c ^ ((((r & 7) ^ ((r >> 2) & 7))) << 3));
}
__device__ __forceinline__ int swzv(int d, int kv) {
  return (d << 6) + (kv ^ ((((d & 7) ^ ((d >> 3) & 7))) << 3));
}

__global__ __launch_bounds__(256)
void attn_k(const float* __restrict__ QKV, const float* __restrict__ mask,
            ush* __restrict__ Oh, ush* __restrict__ Om, ush* __restrict__ Ol,
            int mode)
{
  __shared__ __align__(16) ush smem[4 * 4096];
  __shared__ float kb[64];
  ush* QVh = smem;              // Q planes, overlaid by V^T after prologue
  ush* QVl = smem + 4096;
  ush* KPh = smem + 8192;       // K planes, overlaid by P after QK^T
  ush* KPl = smem + 12288;

  const int tid = threadIdx.x;
  const int lane = tid & 63, wave = tid >> 6;
  const int b = blockIdx.x >> 4, h = blockIdx.x & 15;
  const int q0 = blockIdx.y * 64;
  const int lr = tid >> 2;                 // 0..63
  const int lc = (tid & 3) * 16;           // 0,16,32,48
  const int fr = lane & 15;
  const int fq = (lane >> 4) * 8;
  const int hi4 = (lane >> 4) * 4;
  const int wm = wave * 16;

  {
    const float* qp = QKV + (size_t)(b * Ss + q0 + lr) * QKVN + h * HDd + lc;
#pragma unroll
    for (int hf = 0; hf < 2; ++hf) {
      float4 a = *(const float4*)(qp + hf * 8);
      float4 c4 = *(const float4*)(qp + hf * 8 + 4);
      float vals[8] = {a.x, a.y, a.z, a.w, c4.x, c4.y, c4.z, c4.w};
      v8s hv, lv;
#pragma unroll
      for (int j = 0; j < 8; ++j) {
        float v = vals[j] * 0.125f;
        ush hh = f2bf(v);
        ush ll = f2bf(v - bf2f(hh));
        hv[j] = (short)hh; lv[j] = (short)ll;
      }
      int ix = swz(lr, lc + hf * 8);
      *(v8s*)&QVh[ix] = hv;
      *(v8s*)&QVl[ix] = lv;
    }
  }
  __syncthreads();
  v8s qah[2], qal[2];
#pragma unroll
  for (int kh = 0; kh < 2; ++kh) {
    int ix = swz(wm + fr, kh * 32 + fq);
    qah[kh] = *(const v8s*)&QVh[ix];
    qal[kh] = *(const v8s*)&QVl[ix];
  }

  float m_i[4], l_i[4];
  v4f o_acc[4];
#pragma unroll
  for (int i = 0; i < 4; ++i) {
    m_i[i] = -3.0e38f; l_i[i] = 0.f;
    o_acc[i] = (v4f){0.f, 0.f, 0.f, 0.f};
  }

  for (int kt = 0; kt < Ss / 64; ++kt) {
    const int k0 = kt * 64;
    __syncthreads();
    {
      const float* kp = QKV + 1024 + (size_t)(b * Ss + k0 + lr) * QKVN + h * HDd + lc;
      const float* vp = kp + 1024;
#pragma unroll
      for (int hf = 0; hf < 2; ++hf) {
        float4 a = *(const float4*)(kp + hf * 8);
        float4 c4 = *(const float4*)(kp + hf * 8 + 4);
        float vals[8] = {a.x, a.y, a.z, a.w, c4.x, c4.y, c4.z, c4.w};
        v8s hv, lv;
#pragma unroll
        for (int j = 0; j < 8; ++j) {
          float v = vals[j];
          ush hh = f2bf(v);
          ush ll = f2bf(v - bf2f(hh));
          hv[j] = (short)hh; lv[j] = (short)ll;
        }
        int ix = swz(lr, lc + hf * 8);
        *(v8s*)&KPh[ix] = hv;
        *(v8s*)&KPl[ix] = lv;
      }
#pragma unroll
      for (int hf = 0; hf < 2; ++hf) {
        float4 a = *(const float4*)(vp + hf * 8);
        float4 c4 = *(const float4*)(vp + hf * 8 + 4);
        float vals[8] = {a.x, a.y, a.z, a.w, c4.x, c4.y, c4.z, c4.w};
#pragma unroll
        for (int j = 0; j < 8; ++j) {
          float v = vals[j];
          ush hh = f2bf(v);
          ush ll = f2bf(v - bf2f(hh));
          int d = lc + hf * 8 + j;
          int ix = swzv(d, lr);
          QVh[ix] = hh;
          QVl[ix] = ll;
        }
      }
      if (tid < 64) {
        float mv = mask[b * Ss + k0 + tid];
        kb[tid] = mode ? (mv > 0.f ? 0.f : -1.0e9f) : mv;
      }
    }
    __syncthreads();

    v4f sacc[4] = {};
#pragma unroll
    for (int ni = 0; ni < 4; ++ni) {
#pragma unroll
      for (int kh = 0; kh < 2; ++kh) {
        int ix = swz(ni * 16 + fr, kh * 32 + fq);
        v8s bh = *(const v8s*)&KPh[ix];
        v8s bl = *(const v8s*)&KPl[ix];
        sacc[ni] = __builtin_amdgcn_mfma_f32_16x16x32_bf16(qah[kh], bh, sacc[ni], 0, 0, 0);
        sacc[ni] = __builtin_amdgcn_mfma_f32_16x16x32_bf16(qal[kh], bh, sacc[ni], 0, 0, 0);
        sacc[ni] = __builtin_amdgcn_mfma_f32_16x16x32_bf16(qah[kh], bl, sacc[ni], 0, 0, 0);
      }
    }
    __syncthreads();

    float kbv[4];
#pragma unroll
    for (int ni = 0; ni < 4; ++ni) kbv[ni] = kb[ni * 16 + fr];
#pragma unroll
    for (int r = 0; r < 4; ++r) {
      float s0 = sacc[0][r] + kbv[0];
      float s1 = sacc[1][r] + kbv[1];
      float s2 = sacc[2][r] + kbv[2];
      float s3 = sacc[3][r] + kbv[3];
      float mx = fmaxf(fmaxf(s0, s1), fmaxf(s2, s3));
#pragma unroll
      for (int off = 1; off < 16; off <<= 1) mx = fmaxf(mx, __shfl_xor(mx, off, 64));
      float mnew = fmaxf(m_i[r], mx);
      float p0 = expf(s0 - mnew);
      float p1 = expf(s1 - mnew);
      float p2 = expf(s2 - mnew);
      float p3 = expf(s3 - mnew);
      float sum = p0 + p1 + p2 + p3;
#pragma unroll
      for (int off = 1; off < 16; off <<= 1) sum += __shfl_xor(sum, off, 64);
      float alpha = expf(m_i[r] - mnew);
      l_i[r] = l_i[r] * alpha + sum;
      m_i[r] = mnew;
#pragma unroll
      for (int nj = 0; nj < 4; ++nj) o_acc[nj][r] *= alpha;
      const int qrow = wm + hi4 + r;
      float pv[4] = {p0, p1, p2, p3};
#pragma unroll
      for (int ni = 0; ni < 4; ++ni) {
        ush ph = f2bf(pv[ni]);
        ush pl = f2bf(pv[ni] - bf2f(ph));
        int ix = swz(qrow, ni * 16 + fr);
        KPh[ix] = ph;
        KPl[ix] = pl;
      }
    }
    __syncthreads();

#pragma unroll
    for (int kh = 0; kh < 2; ++kh) {
      int aix = swz(wm + fr, kh * 32 + fq);
      v8s pah = *(const v8s*)&KPh[aix];
      v8s pal = *(const v8s*)&KPl[aix];
#pragma unroll
      for (int nj = 0; nj < 4; ++nj) {
        int vix = swzv(nj * 16 + fr, kh * 32 + fq);
        v8s vh = *(const v8s*)&QVh[vix];
        v8s vl = *(const v8s*)&QVl[vix];
        o_acc[nj] = __builtin_amdgcn_mfma_f32_16x16x32_bf16(pah, vh, o_acc[nj], 0, 0, 0);
        o_acc[nj] = __builtin_amdgcn_mfma_f32_16x16x32_bf16(pal, vh, o_acc[nj], 0, 0, 0);
        o_acc[nj] = __builtin_amdgcn_mfma_f32_16x16x32_bf16(pah, vl, o_acc[nj], 0, 0, 0);
      }
    }
  }

  // ---- epilogue: normalize + split h/m/l planes --------------------------
#pragma unroll
  for (int r = 0; r < 4; ++r) {
    float inv = 1.0f / l_i[r];
    const size_t row = (size_t)(b * Ss + q0 + wm + hi4 + r);
#pragma unroll
    for (int nj = 0; nj < 4; ++nj) {
      float v = o_acc[nj][r] * inv;
      ush ch = f2bf(v);
      float rr = v - bf2f(ch);
      ush cm = f2bf_t(rr);
      ush cl = f2bf_t(rr - bf2f(cm));
      const size_t ix = row * Dd + h * HDd + nj * 16 + fr;
      Oh[ix] = ch;
      Om[ix] = cm;
      Ol[ix] = cl;
    }
  }
}

// ---------------- fused residual-add + LayerNorm ----------------------------
__global__ __launch_bounds__(256)
void ln_k(const float* __restrict__ X, const float* __restrict__ R,
          const float* __restrict__ g, const float* __restrict__ be,
          float* __restrict__ Out)
{
  __shared__ float red[8];
  const int row = blockIdx.x;
  const int tid = threadIdx.x;
  const int d = tid * 4;
  float4 xv = *(const float4*)(X + (size_t)row * Dd + d);
  float4 rv = *(const float4*)(R + (size_t)row * Dd + d);
  float v0 = xv.x + rv.x, v1 = xv.y + rv.y, v2 = xv.z + rv.z, v3 = xv.w + rv.w;
  float sum = v0 + v1 + v2 + v3;
#pragma unroll
  for (int off = 32; off; off >>= 1) sum += __shfl_xor(sum, off, 64);
  const int wave = tid >> 6, lane = tid & 63;
  if (lane == 0) red[wave] = sum;
  __syncthreads();
  float mean = (red[0] + red[1] + red[2] + red[3]) * (1.0f / Dd);
  float d0 = v0 - mean, d1 = v1 - mean, d2 = v2 - mean, d3 = v3 - mean;
  float ss = d0 * d0 + d1 * d1 + d2 * d2 + d3 * d3;
#pragma unroll
  for (int off = 32; off; off >>= 1) ss += __shfl_xor(ss, off, 64);
  if (lane == 0) red[4 + wave] = ss;
  __syncthreads();
  float var = (red[4] + red[5] + red[6] + red[7]) * (1.0f / Dd);
  float inv = 1.0f / sqrtf(var + 1e-5f);
  float4 gv = *(const float4*)(g + d);
  float4 bv = *(const float4*)(be + d);
  float4 r;
  r.x = d0 * inv * gv.x + bv.x;
  r.y = d1 * inv * gv.y + bv.y;
  r.z = d2 * inv * gv.z + bv.z;
  r.w = d3 * inv * gv.w + bv.w;
  *(float4*)&Out[(size_t)row * Dd + d] = r;
}

// ---- LN + h/m/l plane emission (output feeds a gemm6p A operand) -----------
__global__ __launch_bounds__(256)
void ln3_k(const float* __restrict__ X, const float* __restrict__ R,
           const float* __restrict__ g, const float* __restrict__ be,
           float* __restrict__ Out, ush* __restrict__ Ph,
           ush* __restrict__ Pm, ush* __restrict__ Pl)
{
  __shared__ float red[8];
  const int row = blockIdx.x;
  const int tid = threadIdx.x;
  const int d = tid * 4;
  float4 xv = *(const float4*)(X + (size_t)row * Dd + d);
  float4 rv = *(const float4*)(R + (size_t)row * Dd + d);
  float v0 = xv.x + rv.x, v1 = xv.y + rv.y, v2 = xv.z + rv.z, v3 = xv.w + rv.w;
  float sum = v0 + v1 + v2 + v3;
#pragma unroll
  for (int off = 32; off; off >>= 1) sum += __shfl_xor(sum, off, 64);
  const int wave = tid >> 6, lane = tid & 63;
  if (lane == 0) red[wave] = sum;
  __syncthreads();
  float mean = (red[0] + red[1] + red[2] + red[3]) * (1.0f / Dd);
  float d0 = v0 - mean, d1 = v1 - mean, d2 = v2 - mean, d3 = v3 - mean;
  float ss = d0 * d0 + d1 * d1 + d2 * d2 + d3 * d3;
#pragma unroll
  for (int off = 32; off; off >>= 1) ss += __shfl_xor(ss, off, 64);
  if (lane == 0) red[4 + wave] = ss;
  __syncthreads();
  float var = (red[4] + red[5] + red[6] + red[7]) * (1.0f / Dd);
  float inv = 1.0f / sqrtf(var + 1e-5f);
  float4 gv = *(const float4*)(g + d);
  float4 bv = *(const float4*)(be + d);
  float4 r;
  r.x = d0 * inv * gv.x + bv.x;
  r.y = d1 * inv * gv.y + bv.y;
  r.z = d2 * inv * gv.z + bv.z;
  r.w = d3 * inv * gv.w + bv.w;
  *(float4*)&Out[(size_t)row * Dd + d] = r;
  ushort4 h4, m4, l4;
  float rr;
  h4.x = f2bf(r.x); rr = r.x - bf2f(h4.x); m4.x = f2bf_t(rr); l4.x = f2bf_t(rr - bf2f(m4.x));
  h4.y = f2bf(r.y); rr = r.y - bf2f(h4.y); m4.y = f2bf_t(rr); l4.y = f2bf_t(rr - bf2f(m4.y));
  h4.z = f2bf(r.z); rr = r.z - bf2f(h4.z); m4.z = f2bf_t(rr); l4.z = f2bf_t(rr - bf2f(m4.z));
  h4.w = f2bf(r.w); rr = r.w - bf2f(h4.w); m4.w = f2bf_t(rr); l4.w = f2bf_t(rr - bf2f(m4.w));
  const size_t po = (size_t)row * Dd + d;
  *(ushort4*)&Ph[po] = h4;
  *(ushort4*)&Pm[po] = m4;
  *(ushort4*)&Pl[po] = l4;
}

// ---------------- per-token sigmoid score -----------------------------------
__global__ __launch_bounds__(256)
void score_k(const float* __restrict__ F, const float* __restrict__ Wsv,
             const float* __restrict__ bs, float* __restrict__ Sout)
{
  const int tok = blockIdx.x * 4 + (threadIdx.x >> 6);
  const int lane = threadIdx.x & 63;
  const float* fp = F + (size_t)tok * Dd;
  float acc = 0.f;
#pragma unroll
  for (int ii = 0; ii < 16; ++ii) {
    int d = lane + ii * 64;
    acc += fp[d] * Wsv[d];
  }
#pragma unroll
  for (int off = 32; off; off >>= 1) acc += __shfl_xor(acc, off, 64);
  if (lane == 0) Sout[tok] = 1.0f / (1.0f + expf(-(acc + bs[0])));
}

// ---------------- per-batch scan: sv, seg, new_mask, nact -------------------
__global__ __launch_bounds__(256)
void scan_k(const float* __restrict__ sin, const float* __restrict__ mask,
            float* __restrict__ svout, int* __restrict__ segout,
            float* __restrict__ nmask, int* __restrict__ nact)
{
  __shared__ double sc[256];
  __shared__ float mxs[256];
  const int b = blockIdx.x;
  const int tid = threadIdx.x;
  const int t0 = tid * 4;
  float svl[4], mk[4];
  double loc[4];
  double run = 0.0;
#pragma unroll
  for (int i = 0; i < 4; i++) {
    float s = sin[b * Ss + t0 + i];
    float m = mask[b * Ss + t0 + i];
    float sv = (m > 0.f) ? s : 0.f;
    svl[i] = sv; mk[i] = m;
    run += (double)sv;
    loc[i] = run;
  }
  sc[tid] = run;
  __syncthreads();
  for (int off = 1; off < 256; off <<= 1) {
    double add = (tid >= off) ? sc[tid - off] : 0.0;
    __syncthreads();
    sc[tid] += add;
    __syncthreads();
  }
  double excl = sc[tid] - run;
  float lmax = -1.0f;
#pragma unroll
  for (int i = 0; i < 4; i++) {
    double c = floor(excl + loc[i]);
    int sg = (int)c;
    if (sg < 0) sg = 0;
    if (sg > Ss - 1) sg = Ss - 1;
    svout[b * Ss + t0 + i] = svl[i];
    segout[b * Ss + t0 + i] = sg;
    if (mk[i] > 0.f) lmax = fmaxf(lmax, (float)c);
  }
  mxs[tid] = lmax;
  __syncthreads();
  for (int off = 128; off; off >>= 1) {
    if (tid < off) mxs[tid] = fmaxf(mxs[tid], mxs[tid + off]);
    __syncthreads();
  }
  float mseg = mxs[0];
  if (tid == 0) {
    int na = (int)mseg + 1;
    if (na < 1) na = 1;
    if (na > Ss) na = Ss;
    nact[b] = na;
  }
#pragma unroll
  for (int i = 0; i < 4; i++)
    nmask[b * Ss + t0 + i] = ((float)(t0 + i) <= mseg) ? 1.0f : 0.0f;
}

// ---------------- weighted segment scatter-add ------------------------------
__global__ __launch_bounds__(256)
void scatter_k(const float* __restrict__ X, const float* __restrict__ sv,
               const int* __restrict__ seg, float* __restrict__ pooled)
{
  const int tok = blockIdx.x;
  const float w = sv[tok];
  if (w == 0.f) return;
  const int b = tok >> 10;
  const int sg = seg[tok];
  const int d = threadIdx.x * 4;
  float4 xv = *(const float4*)(X + (size_t)tok * Dd + d);
  float* pp = pooled + ((size_t)(b * Ss + sg)) * Dd + d;
  atomicAdd(pp + 0, xv.x * w);
  atomicAdd(pp + 1, xv.y * w);
  atomicAdd(pp + 2, xv.z * w);
  atomicAdd(pp + 3, xv.w * w);
}

// ---------------- small helpers: bias concat, const rows --------------------
__global__ __launch_bounds__(256)
void bcat_k(const float* __restrict__ bq, const float* __restrict__ bk,
            const float* __restrict__ bv, float* __restrict__ out)
{
  int i = blockIdx.x * 256 + threadIdx.x;     // 3072 total
  float v = (i < 1024) ? bq[i] : (i < 2048) ? bk[i - 1024] : bv[i - 2048];
  out[i] = v;
}
__global__ __launch_bounds__(256)
void cv1_k(const float* __restrict__ bp1, float* __restrict__ cv1)
{
  int i = blockIdx.x * 256 + threadIdx.x;     // 4096
  cv1[i] = gelu_f(bp1[i]);
}
// cv2[col] = sum_k cv1[k]*(P2T_h+P2T_l)[col][k] + bp2[col]; 4 cols/block
__global__ __launch_bounds__(256)
void cv2_k(const float* __restrict__ cv1, const ush* __restrict__ p2h,
           const ush* __restrict__ p2l, const float* __restrict__ bp2,
           float* __restrict__ cv2)
{
  const int col = blockIdx.x * 4 + (threadIdx.x >> 6);
  const int lane = threadIdx.x & 63;
  const ush* rh = p2h + (size_t)col * HIDh;
  const ush* rl = p2l + (size_t)col * HIDh;
  float acc = 0.f;
#pragma unroll
  for (int ii = 0; ii < 64; ++ii) {
    int k = lane + ii * 64;
    acc += cv1[k] * (bf2f(rh[k]) + bf2f(rl[k]));
  }
#pragma unroll
  for (int off = 32; off; off >>= 1) acc += __shfl_xor(acc, off, 64);
  if (lane == 0) cv2[col] = acc + bp2[col];
}

extern "C" void kernel_launch(void* const* d_in, const int* in_sizes, int n_in,
                              void* d_out, int out_size, void* d_ws, size_t ws_size,
                              hipStream_t stream)
{
  const float* x     = (const float*)d_in[0];
  const float* masks = (const float*)d_in[1];
  const float* Wq  = (const float*)d_in[2];
  const float* bq  = (const float*)d_in[3];
  const float* Wk  = (const float*)d_in[4];
  const float* bk  = (const float*)d_in[5];
  const float* Wv  = (const float*)d_in[6];
  const float* bv  = (const float*)d_in[7];
  const float* Wo  = (const float*)d_in[8];
  const float* bo  = (const float*)d_in[9];
  const float* g1  = (const float*)d_in[10];
  const float* be1 = (const float*)d_in[11];
  const float* g2  = (const float*)d_in[12];
  const float* be2 = (const float*)d_in[13];
  const float* W1  = (const float*)d_in[14];
  const float* bf1 = (const float*)d_in[15];
  const float* W2  = (const float*)d_in[16];
  const float* bf2 = (const float*)d_in[17];
  const float* Wsp = (const float*)d_in[18];
  const float* bs  = (const float*)d_in[19];
  const float* P1  = (const float*)d_in[20];
  const float* bp1 = (const float*)d_in[21];
  const float* P2  = (const float*)d_in[22];
  const float* bp2 = (const float*)d_in[23];

  // ---- workspace layout ----------------------------------------------------
  // w3: 24M ush (48MB) weight planes. ub: u0..u5 (6 x ND floats). smalls after.
  // PLANE UNIT: PL = ND ush (8.39MB, one 1024-col bf16 plane). Slab u_i =
  // ubu[2i*PL .. (2i+2)*PL). All encoder intermediates live as h/m/l planes in
  // half-slab granularity; liveness verified per step (see round-8 notes).
  const size_t UW = (size_t)Dd * Dd;        // 1,048,576
  const size_t ND = (size_t)NTOK * Dd;      // 4,194,304
  const size_t PL = ND;                     // ush per 1024-col plane
  ush* w3 = (ush*)d_ws;
  ush *wqkvh = w3 + 0*UW, *wqkvm = w3 + 3*UW, *wqkvl = w3 + 6*UW;
  ush *woh = w3 + 9*UW,  *wom = w3 + 10*UW, *wol = w3 + 11*UW;
  ush *w1h = w3 + 12*UW, *w1m = w3 + 14*UW, *w1l = w3 + 16*UW;
  ush *w2h = w3 + 18*UW, *w2m = w3 + 20*UW, *w2l = w3 + 22*UW;
  float* ub = (float*)(w3 + 24*UW);
  ush*   ubu = (ush*)ub;
  float* sm = ub + 6 * ND;
  float* sbuf = sm;                  // NTOK
  float* svb  = sm + NTOK;           // NTOK
  int*   segb = (int*)(sm + 2 * NTOK);
  int*   nact = (int*)(sm + 3 * NTOK);           // 4 ints
  float* bqkv = sm + 3 * NTOK + 16;              // 3072
  float* cv1  = bqkv + QKVN;                     // 4096
  float* cv2  = cv1 + HIDh;                      // 4096

  float* outp = (float*)d_out;
  float* nmask = outp + (size_t)NTOK * HIDh;

  // ---- weight prep ---------------------------------------------------------
  hipLaunchKernelGGL(wt3_k, dim3(Dd/32, Dd/32), dim3(256), 0, stream, Wq, wqkvh,        wqkvm,        wqkvl,        Dd, Dd);
  hipLaunchKernelGGL(wt3_k, dim3(Dd/32, Dd/32), dim3(256), 0, stream, Wk, wqkvh + UW,   wqkvm + UW,   wqkvl + UW,   Dd, Dd);
  hipLaunchKernelGGL(wt3_k, dim3(Dd/32, Dd/32), dim3(256), 0, stream, Wv, wqkvh + 2*UW, wqkvm + 2*UW, wqkvl + 2*UW, Dd, Dd);
  hipLaunchKernelGGL(wt3_k, dim3(Dd/32, Dd/32), dim3(256), 0, stream, Wo, woh, wom, wol, Dd, Dd);
  hipLaunchKernelGGL(wt3_k, dim3(FFf/32, Dd/32), dim3(256), 0, stream, W1, w1h, w1m, w1l, Dd, FFf);
  hipLaunchKernelGGL(wt3_k, dim3(Dd/32, FFf/32), dim3(256), 0, stream, W2, w2h, w2m, w2l, FFf, Dd);
  hipLaunchKernelGGL(bcat_k, dim3(QKVN/256), dim3(256), 0, stream, bq, bk, bv, bqkv);
  hipLaunchKernelGGL(cv1_k, dim3(HIDh/256), dim3(256), 0, stream, bp1, cv1);

  // ======================= PASS 1 (float mask added) ========================
  // xs1 planes [0,PL,2PL); qkv1 f32 [4PL..10PL); ao1 planes (10PL,11PL,3PL);
  // t1 f32 [4PL..6PL); hb f32 [6PL..8PL); hb planes (8PL,9PL,0);
  // ffh planes (4PL,10PL,2PL) each 2PL wide; t1b f32 [8PL..10PL);
  // feat1 f32 [0..2PL) + feat1(xs2) planes (2PL,3PL,4PL).
  hipLaunchKernelGGL(psplit3_k, dim3(NTOK), dim3(256), 0, stream,
                     x, ubu + 0, ubu + PL, ubu + 2*PL);
  hipLaunchKernelGGL((gemm6p_k<0,0,128>), dim3(QKVN/128, NTOK/128), dim3(256), 0, stream,
                     ubu + 0, ubu + PL, ubu + 2*PL, wqkvh, wqkvm, wqkvl, bqkv,
                     (void*)(float*)(ubu + 4*PL), nullptr, nullptr, NTOK, QKVN, Dd);
  hipLaunchKernelGGL(attn_k, dim3(Bb * Hh, Ss / 64), dim3(256), 0, stream,
                     (const float*)(ubu + 4*PL), masks,
                     ubu + 10*PL, ubu + 11*PL, ubu + 3*PL, 0);
  hipLaunchKernelGGL((gemm6p_k<0,0,64>), dim3(Dd/64, NTOK/128), dim3(256), 0, stream,
                     ubu + 10*PL, ubu + 11*PL, ubu + 3*PL, woh, wom, wol, bo,
                     (void*)(float*)(ubu + 4*PL), nullptr, nullptr, NTOK, Dd, Dd);
  hipLaunchKernelGGL(ln3_k, dim3(NTOK), dim3(256), 0, stream,
                     (const float*)(ubu + 4*PL), x, g1, be1,
                     (float*)(ubu + 6*PL), ubu + 8*PL, ubu + 9*PL, ubu + 0);
  hipLaunchKernelGGL((gemm6p_k<1,1,128>), dim3(FFf/128, NTOK/128), dim3(256), 0, stream,
                     ubu + 8*PL, ubu + 9*PL, ubu + 0, w1h, w1m, w1l, bf1,
                     (void*)(ubu + 4*PL), (void*)(ubu + 10*PL), (void*)(ubu + 2*PL),
                     NTOK, FFf, Dd);
  hipLaunchKernelGGL((gemm6p_k<0,0,64>), dim3(Dd/64, NTOK/128), dim3(256), 0, stream,
                     ubu + 4*PL, ubu + 10*PL, ubu + 2*PL, w2h, w2m, w2l, bf2,
                     (void*)(float*)(ubu + 8*PL), nullptr, nullptr, NTOK, Dd, FFf);
  hipLaunchKernelGGL(ln3_k, dim3(NTOK), dim3(256), 0, stream,
                     (const float*)(ubu + 8*PL), (const float*)(ubu + 6*PL), g2, be2,
                     (float*)(ubu + 0), ubu + 2*PL, ubu + 3*PL, ubu + 4*PL);

  // ======================= PASS 2 (0/-1e9 mask) =============================
  // xs2 planes (2PL,3PL,4PL) from pass-1 ln2; feat1 f32 [0..2PL);
  // qkv2 f32 [6PL..12PL); ao2 planes (5PL,2PL,3PL); t12 f32 [6PL..8PL);
  // hb2 f32 [8PL..10PL); hb2 planes (10PL,11PL,2PL);
  // ffh2 planes (0,4PL,6PL) each 2PL; t1b2 f32 [2PL..4PL); feat2 [10PL..12PL).
  hipLaunchKernelGGL((gemm6p_k<0,0,128>), dim3(QKVN/128, NTOK/128), dim3(256), 0, stream,
                     ubu + 2*PL, ubu + 3*PL, ubu + 4*PL, wqkvh, wqkvm, wqkvl, bqkv,
                     (void*)(float*)(ubu + 6*PL), nullptr, nullptr, NTOK, QKVN, Dd);
  hipLaunchKernelGGL(attn_k, dim3(Bb * Hh, Ss / 64), dim3(256), 0, stream,
                     (const float*)(ubu + 6*PL), masks,
                     ubu + 5*PL, ubu + 2*PL, ubu + 3*PL, 1);
  hipLaunchKernelGGL((gemm6p_k<0,0,64>), dim3(Dd/64, NTOK/128), dim3(256), 0, stream,
                     ubu + 5*PL, ubu + 2*PL, ubu + 3*PL, woh, wom, wol, bo,
                     (void*)(float*)(ubu + 6*PL), nullptr, nullptr, NTOK, Dd, Dd);
  hipLaunchKernelGGL(ln3_k, dim3(NTOK), dim3(256), 0, stream,
                     (const float*)(ubu + 6*PL), (const float*)(ubu + 0), g1, be1,
                     (float*)(ubu + 8*PL), ubu + 10*PL, ubu + 11*PL, ubu + 2*PL);
  hipLaunchKernelGGL((gemm6p_k<1,1,128>), dim3(FFf/128, NTOK/128), dim3(256), 0, stream,
                     ubu + 10*PL, ubu + 11*PL, ubu + 2*PL, w1h, w1m, w1l, bf1,
                     (void*)(ubu + 0), (void*)(ubu + 4*PL), (void*)(ubu + 6*PL),
                     NTOK, FFf, Dd);
  hipLaunchKernelGGL((gemm6p_k<0,0,64>), dim3(Dd/64, NTOK/128), dim3(256), 0, stream,
                     ubu + 0, ubu + 4*PL, ubu + 6*PL, w2h, w2m, w2l, bf2,
                     (void*)(float*)(ubu + 2*PL), nullptr, nullptr, NTOK, Dd, FFf);
  hipLaunchKernelGGL(ln_k, dim3(NTOK), dim3(256), 0, stream,
                     (const float*)(ubu + 2*PL), (const float*)(ubu + 8*PL), g2, be2,
                     (float*)(ubu + 10*PL));

  // ======================= pooling + projector ==============================
  float* feat2  = (float*)(ubu + 10*PL);
  float* pooled = (float*)(ubu + 0);
  hipLaunchKernelGGL(score_k, dim3(NTOK / 4), dim3(256), 0, stream, feat2, Wsp, bs, sbuf);
  hipLaunchKernelGGL(scan_k, dim3(Bb), dim3(256), 0, stream, sbuf, masks, svb, segb, nmask, nact);
  hipMemsetAsync(pooled, 0, ND * sizeof(float), stream);
  hipLaunchKernelGGL(scatter_k, dim3(NTOK), dim3(256), 0, stream, x, svb, segb, pooled);

  ush* ph    = ubu + 4*PL;           // pooled planes (u2)
  ush* pl_   = ubu + 5*PL;
  ush* hid_h = ubu + 6*PL;           // [6PL..10PL)
  ush* hid_l = ubu + 0;              // [0..4PL)
  ush* p1h = w3;                     // 4M ush
  ush* p1l = w3 + 4*UW;
  ush* p2h = (ush*)d_ws;             // 16M ush each plane
  ush* p2l = p2h + (size_t)HIDh * HIDh;

  hipLaunchKernelGGL(psplit_k, dim3(NTOK), dim3(256), 0, stream, pooled, ph, pl_);
  hipLaunchKernelGGL(wt_k, dim3(HIDh / 32, Dd / 32), dim3(256), 0, stream, P1, p1h, p1l, Dd, HIDh);
  hipLaunchKernelGGL((gemm3p_k<1>), dim3(HIDh / 128, NTOK / 128), dim3(256), 0, stream,
                     ph, pl_, p1h, p1l, bp1, (void*)hid_h, (void*)hid_l,
                     NTOK, HIDh, Dd, nact, cv1);
  hipLaunchKernelGGL(wt_k, dim3(HIDh / 32, HIDh / 32), dim3(256), 0, stream, P2, p2h, p2l, HIDh, HIDh);
  hipLaunchKernelGGL(cv2_k, dim3(HIDh / 4), dim3(256), 0, stream, cv1, p2h, p2l, bp2, cv2);
  hipLaunchKernelGGL((gemm3p_k<0>), dim3(HIDh / 128, NTOK / 128), dim3(256), 0, stream,
                     hid_h, hid_l, p2h, p2l, bp2, (void*)outp, nullptr,
                     NTOK, HIDh, HIDh, nact, cv2);
}

// Round 9
// 1676.794 us; speedup vs baseline: 1.0377x; 1.0377x over previous
//
#include <hip/hip_runtime.h>

#define Bb 4
#define Ss 1024
#define Dd 1024
#define Hh 16
#define HDd 64
#define FFf 2048
#define HIDh 4096
#define NTOK (Bb*Ss)
#define QKVN 3072

typedef unsigned short ush;
typedef short v8s __attribute__((ext_vector_type(8)));
typedef float v4f __attribute__((ext_vector_type(4)));

__device__ __forceinline__ float gelu_f(float x) {
  return 0.5f * x * (1.0f + erff(x * 0.70710678118654752f));
}
__device__ __forceinline__ ush f2bf(float x) {              // RNE
  unsigned int u = __float_as_uint(x);
  u += 0x7FFFu + ((u >> 16) & 1u);
  return (ush)(u >> 16);
}
__device__ __forceinline__ ush f2bf_t(float x) {            // truncate
  return (ush)(__float_as_uint(x) >> 16);
}
__device__ __forceinline__ float bf2f(ush h) {
  return __uint_as_float(((unsigned int)h) << 16);
}
__device__ __forceinline__ void gload16(const void* g, void* l) {
  __builtin_amdgcn_global_load_lds(
      (const __attribute__((address_space(1))) unsigned int*)g,
      (__attribute__((address_space(3))) unsigned int*)l, 16, 0, 0);
}

// ---------------- bf16x6 split GEMM (fp32-fidelity, encoder path) -----------
// BN=128: 128x128 tile, 4 waves as 2x2 of 64x64. BN=64: 128x64 tile, waves
// 2x2 of 64x32. Used for Wo/W1/W2 (f32 A, in-loop conversion; these run at
// 3-4 blocks/CU where wave-overlap hides the latency). R8 lesson: pre-split
// planes for these REGRESSED (producers are memory-bound; extra plane writes
// cost more than the removed VALU) -- keep in-loop conversion here.
template<int GELU, int BN>
__global__ __launch_bounds__(256)
void gemm6_k(const float* __restrict__ A, const ush* __restrict__ Bh,
             const ush* __restrict__ Bm, const ush* __restrict__ Bl,
             const float* __restrict__ bias, float* __restrict__ C,
             int M, int N, int K)
{
  constexpr int NI = BN / 32;                 // n-tiles per wave
  __shared__ __align__(16) ush As0[128 * 32];
  __shared__ __align__(16) ush As1[128 * 32];
  __shared__ __align__(16) ush As2[128 * 32];
  __shared__ __align__(16) ush Bs0[BN * 32];
  __shared__ __align__(16) ush Bs1[BN * 32];
  __shared__ __align__(16) ush Bs2[BN * 32];
  const int tid = threadIdx.x;
  const int lane = tid & 63, wave = tid >> 6;
  const int bm = blockIdx.y * 128, bn = blockIdx.x * BN;
  const int wm = (wave & 1) * 64, wn = (wave >> 1) * (BN / 2);

  v4f acc[4][NI] = {};

  const int ma = tid >> 3;             // 0..31
  const int ka = (tid & 7) * 4;        // 0..28
  const float* Ap = A + (size_t)(bm + ma) * K + ka;

  const int nb = bn + wave * (BN / 4) + (lane >> 2);
  const int kb = (lane & 3) * 8;
  const ush* gh0 = Bh + (size_t)nb * K + kb;
  const ush* gm0 = Bm + (size_t)nb * K + kb;
  const ush* gl0 = Bl + (size_t)nb * K + kb;
  const size_t row16 = (size_t)16 * K;
  ush* lbh = &Bs0[wave * (BN / 4) * 32];
  ush* lbm = &Bs1[wave * (BN / 4) * 32];
  ush* lbl = &Bs2[wave * (BN / 4) * 32];

  const int fr = lane & 15;
  const int fq = (lane >> 4) * 8;

  for (int k0 = 0; k0 < K; k0 += 32) {
#pragma unroll
    for (int c = 0; c < BN / 64; ++c) {
      gload16(gh0 + c * row16 + k0, lbh + c * 512);
      gload16(gm0 + c * row16 + k0, lbm + c * 512);
      gload16(gl0 + c * row16 + k0, lbl + c * 512);
    }
#pragma unroll
    for (int p = 0; p < 4; ++p) {
      float4 v = *(const float4*)(Ap + (size_t)p * 32 * K + k0);
      ushort4 h, m, l;
      float r;
      h.x = f2bf(v.x); r = v.x - bf2f(h.x); m.x = f2bf_t(r); l.x = f2bf_t(r - bf2f(m.x));
      h.y = f2bf(v.y); r = v.y - bf2f(h.y); m.y = f2bf_t(r); l.y = f2bf_t(r - bf2f(m.y));
      h.z = f2bf(v.z); r = v.z - bf2f(h.z); m.z = f2bf_t(r); l.z = f2bf_t(r - bf2f(m.z));
      h.w = f2bf(v.w); r = v.w - bf2f(h.w); m.w = f2bf_t(r); l.w = f2bf_t(r - bf2f(m.w));
      const int off = (ma + p * 32) * 32 + ka;
      *(ushort4*)&As0[off] = h;
      *(ushort4*)&As1[off] = m;
      *(ushort4*)&As2[off] = l;
    }
    __syncthreads();
    v8s ah[4], am[4], al[4];
#pragma unroll
    for (int mi = 0; mi < 4; ++mi) {
      const int o = (wm + mi * 16 + fr) * 32 + fq;
      ah[mi] = *(const v8s*)&As0[o];
      am[mi] = *(const v8s*)&As1[o];
      al[mi] = *(const v8s*)&As2[o];
    }
#pragma unroll
    for (int ni = 0; ni < NI; ++ni) {
      const int o = (wn + ni * 16 + fr) * 32 + fq;
      v8s bh = *(const v8s*)&Bs0[o];
      v8s bm_ = *(const v8s*)&Bs1[o];
      v8s bl = *(const v8s*)&Bs2[o];
#pragma unroll
      for (int mi = 0; mi < 4; ++mi) {
        acc[mi][ni] = __builtin_amdgcn_mfma_f32_16x16x32_bf16(ah[mi], bh,  acc[mi][ni], 0, 0, 0);
        acc[mi][ni] = __builtin_amdgcn_mfma_f32_16x16x32_bf16(ah[mi], bm_, acc[mi][ni], 0, 0, 0);
        acc[mi][ni] = __builtin_amdgcn_mfma_f32_16x16x32_bf16(am[mi], bh,  acc[mi][ni], 0, 0, 0);
        acc[mi][ni] = __builtin_amdgcn_mfma_f32_16x16x32_bf16(ah[mi], bl,  acc[mi][ni], 0, 0, 0);
        acc[mi][ni] = __builtin_amdgcn_mfma_f32_16x16x32_bf16(al[mi], bh,  acc[mi][ni], 0, 0, 0);
        acc[mi][ni] = __builtin_amdgcn_mfma_f32_16x16x32_bf16(am[mi], bm_, acc[mi][ni], 0, 0, 0);
      }
    }
    __syncthreads();
  }
  const int eq = (lane >> 4) * 4;
#pragma unroll
  for (int ni = 0; ni < NI; ++ni) {
    const int col = bn + wn + ni * 16 + fr;
    const float bv = bias[col];
#pragma unroll
    for (int mi = 0; mi < 4; ++mi) {
      const int row0 = bm + wm + mi * 16 + eq;
#pragma unroll
      for (int r = 0; r < 4; ++r) {
        float v = acc[mi][ni][r] + bv;
        if (GELU) v = gelu_f(v);
        C[(size_t)(row0 + r) * N + col] = v;
      }
    }
  }
}

// ---------------- encoder QKV GEMM: pre-split bf16x6, all-DMA ---------------
// QKV only: the x/feat1 pre-split (psplit3) is a cheap standalone pass whose
// cost (<5us) is far below the 24-n-block-redundant in-loop conversion it
// removes (proven -33us at R5).
__global__ __launch_bounds__(256)
void gemm6p_k(const ush* __restrict__ Ah, const ush* __restrict__ Am,
              const ush* __restrict__ Al, const ush* __restrict__ Bh,
              const ush* __restrict__ Bm, const ush* __restrict__ Bl,
              const float* __restrict__ bias, float* __restrict__ C,
              int M, int N, int K)
{
  __shared__ __align__(16) ush As0[128 * 32];
  __shared__ __align__(16) ush As1[128 * 32];
  __shared__ __align__(16) ush As2[128 * 32];
  __shared__ __align__(16) ush Bs0[128 * 32];
  __shared__ __align__(16) ush Bs1[128 * 32];
  __shared__ __align__(16) ush Bs2[128 * 32];
  const int tid = threadIdx.x;
  const int lane = tid & 63, wave = tid >> 6;
  const int bm = blockIdx.y * 128, bn = blockIdx.x * 128;
  const int wm = (wave & 1) * 64, wn = (wave >> 1) * 64;

  v4f acc[4][4] = {};

  const int rsr = wave * 32 + (lane >> 2);   // staged row (of 128)
  const int ks = (lane & 3) * 8;
  const ush* gAh = Ah + (size_t)(bm + rsr) * K + ks;
  const ush* gAm = Am + (size_t)(bm + rsr) * K + ks;
  const ush* gAl = Al + (size_t)(bm + rsr) * K + ks;
  const ush* gBh = Bh + (size_t)(bn + rsr) * K + ks;
  const ush* gBm = Bm + (size_t)(bn + rsr) * K + ks;
  const ush* gBl = Bl + (size_t)(bn + rsr) * K + ks;
  const size_t row16 = (size_t)16 * K;
  const int lo = wave * 1024;

  const int fr = lane & 15;
  const int fq = (lane >> 4) * 8;

  for (int k0 = 0; k0 < K; k0 += 32) {
    gload16(gAh + k0, &As0[lo]); gload16(gAh + row16 + k0, &As0[lo + 512]);
    gload16(gAm + k0, &As1[lo]); gload16(gAm + row16 + k0, &As1[lo + 512]);
    gload16(gAl + k0, &As2[lo]); gload16(gAl + row16 + k0, &As2[lo + 512]);
    gload16(gBh + k0, &Bs0[lo]); gload16(gBh + row16 + k0, &Bs0[lo + 512]);
    gload16(gBm + k0, &Bs1[lo]); gload16(gBm + row16 + k0, &Bs1[lo + 512]);
    gload16(gBl + k0, &Bs2[lo]); gload16(gBl + row16 + k0, &Bs2[lo + 512]);
    __syncthreads();
    v8s ah[4], am[4], al[4];
#pragma unroll
    for (int mi = 0; mi < 4; ++mi) {
      const int o = (wm + mi * 16 + fr) * 32 + fq;
      ah[mi] = *(const v8s*)&As0[o];
      am[mi] = *(const v8s*)&As1[o];
      al[mi] = *(const v8s*)&As2[o];
    }
#pragma unroll
    for (int ni = 0; ni < 4; ++ni) {
      const int o = (wn + ni * 16 + fr) * 32 + fq;
      v8s bh = *(const v8s*)&Bs0[o];
      v8s bm_ = *(const v8s*)&Bs1[o];
      v8s bl = *(const v8s*)&Bs2[o];
#pragma unroll
      for (int mi = 0; mi < 4; ++mi) {
        acc[mi][ni] = __builtin_amdgcn_mfma_f32_16x16x32_bf16(ah[mi], bh,  acc[mi][ni], 0, 0, 0);
        acc[mi][ni] = __builtin_amdgcn_mfma_f32_16x16x32_bf16(ah[mi], bm_, acc[mi][ni], 0, 0, 0);
        acc[mi][ni] = __builtin_amdgcn_mfma_f32_16x16x32_bf16(am[mi], bh,  acc[mi][ni], 0, 0, 0);
        acc[mi][ni] = __builtin_amdgcn_mfma_f32_16x16x32_bf16(ah[mi], bl,  acc[mi][ni], 0, 0, 0);
        acc[mi][ni] = __builtin_amdgcn_mfma_f32_16x16x32_bf16(al[mi], bh,  acc[mi][ni], 0, 0, 0);
        acc[mi][ni] = __builtin_amdgcn_mfma_f32_16x16x32_bf16(am[mi], bm_, acc[mi][ni], 0, 0, 0);
      }
    }
    __syncthreads();
  }
  const int eq = (lane >> 4) * 4;
#pragma unroll
  for (int ni = 0; ni < 4; ++ni) {
    const int col = bn + wn + ni * 16 + fr;
    const float bv = bias[col];
#pragma unroll
    for (int mi = 0; mi < 4; ++mi) {
      const int row0 = bm + wm + mi * 16 + eq;
#pragma unroll
      for (int r = 0; r < 4; ++r)
        C[(size_t)(row0 + r) * N + col] = acc[mi][ni][r] + bv;
    }
  }
}

// ---------------- projector GEMM (R4-proven): 128x128, dbuf, nact skip ------
// A/B pre-split bf16 h/l planes, all-DMA staging, double-buffered LDS with
// prefetch-before-compute. 2D grid with per-block nact skip. Runs at the
// m97-structure ceiling (~876 TF); BN=64 (R5) and grid-compaction (R7) both
// regressed it -- this exact config is the verified optimum.
// MODE 0: f32 out (P2). MODE 1: gelu + split bf16 h/l out planes (P1).
template<int MODE>
__global__ __launch_bounds__(256)
void gemm3p_k(const ush* __restrict__ Ah, const ush* __restrict__ Al,
              const ush* __restrict__ Bh, const ush* __restrict__ Bl,
              const float* __restrict__ bias, void* C0v, void* C1v,
              int M, int N, int K,
              const int* __restrict__ nact, const float* __restrict__ cvec)
{
  const int tid = threadIdx.x;
  const int bm = blockIdx.y * 128, bn = blockIdx.x * 128;
  if ((bm & (Ss - 1)) >= nact[bm >> 10]) {
    const int col = bn + (tid & 31) * 4;
    float4 cv = *(const float4*)&cvec[col];
    if (MODE == 0) {
      float* C = (float*)C0v;
#pragma unroll
      for (int i = 0; i < 16; ++i) {
        int row = bm + (tid >> 5) + i * 8;
        *(float4*)&C[(size_t)row * N + col] = cv;
      }
    } else {
      ush* Ch = (ush*)C0v; ush* Cl = (ush*)C1v;
      ushort4 hv, lv;
      hv.x = f2bf(cv.x); lv.x = f2bf(cv.x - bf2f(hv.x));
      hv.y = f2bf(cv.y); lv.y = f2bf(cv.y - bf2f(hv.y));
      hv.z = f2bf(cv.z); lv.z = f2bf(cv.z - bf2f(hv.z));
      hv.w = f2bf(cv.w); lv.w = f2bf(cv.w - bf2f(hv.w));
#pragma unroll
      for (int i = 0; i < 16; ++i) {
        int row = bm + (tid >> 5) + i * 8;
        *(ushort4*)&Ch[(size_t)row * N + col] = hv;
        *(ushort4*)&Cl[(size_t)row * N + col] = lv;
      }
    }
    return;
  }
  __shared__ __align__(16) ush As0[2][128 * 32];
  __shared__ __align__(16) ush As1[2][128 * 32];
  __shared__ __align__(16) ush Bs0[2][128 * 32];
  __shared__ __align__(16) ush Bs1[2][128 * 32];
  const int lane = tid & 63, wave = tid >> 6;
  const int wm = (wave & 1) * 64, wn = (wave >> 1) * 64;

  v4f acc[4][4] = {};

  const int rs = wave * 32 + (lane >> 2);
  const int ks = (lane & 3) * 8;
  const ush* gAh = Ah + (size_t)(bm + rs) * K + ks;
  const ush* gAl = Al + (size_t)(bm + rs) * K + ks;
  const ush* gBh = Bh + (size_t)(bn + rs) * K + ks;
  const ush* gBl = Bl + (size_t)(bn + rs) * K + ks;
  const size_t row16 = (size_t)16 * K;
  const int lbo0 = wave * 1024;
  const int lbo1 = wave * 1024 + 512;

  const int fr = lane & 15;
  const int fq = (lane >> 4) * 8;
  const int nt = K / 32;

  gload16(gAh, &As0[0][lbo0]); gload16(gAh + row16, &As0[0][lbo1]);
  gload16(gAl, &As1[0][lbo0]); gload16(gAl + row16, &As1[0][lbo1]);
  gload16(gBh, &Bs0[0][lbo0]); gload16(gBh + row16, &Bs0[0][lbo1]);
  gload16(gBl, &Bs1[0][lbo0]); gload16(gBl + row16, &Bs1[0][lbo1]);

  for (int t = 0; t < nt; ++t) {
    __syncthreads();
    const int cur = t & 1;
    if (t + 1 < nt) {
      const int nxt = cur ^ 1;
      const int k1 = (t + 1) * 32;
      gload16(gAh + k1, &As0[nxt][lbo0]); gload16(gAh + row16 + k1, &As0[nxt][lbo1]);
      gload16(gAl + k1, &As1[nxt][lbo0]); gload16(gAl + row16 + k1, &As1[nxt][lbo1]);
      gload16(gBh + k1, &Bs0[nxt][lbo0]); gload16(gBh + row16 + k1, &Bs0[nxt][lbo1]);
      gload16(gBl + k1, &Bs1[nxt][lbo0]); gload16(gBl + row16 + k1, &Bs1[nxt][lbo1]);
    }
    v8s afh[4], afl[4];
#pragma unroll
    for (int mi = 0; mi < 4; ++mi) {
      const int o = (wm + mi * 16 + fr) * 32 + fq;
      afh[mi] = *(const v8s*)&As0[cur][o];
      afl[mi] = *(const v8s*)&As1[cur][o];
    }
#pragma unroll
    for (int ni = 0; ni < 4; ++ni) {
      const int o = (wn + ni * 16 + fr) * 32 + fq;
      v8s bh = *(const v8s*)&Bs0[cur][o];
      v8s bl = *(const v8s*)&Bs1[cur][o];
#pragma unroll
      for (int mi = 0; mi < 4; ++mi) {
        acc[mi][ni] = __builtin_amdgcn_mfma_f32_16x16x32_bf16(afh[mi], bh, acc[mi][ni], 0, 0, 0);
        acc[mi][ni] = __builtin_amdgcn_mfma_f32_16x16x32_bf16(afh[mi], bl, acc[mi][ni], 0, 0, 0);
        acc[mi][ni] = __builtin_amdgcn_mfma_f32_16x16x32_bf16(afl[mi], bh, acc[mi][ni], 0, 0, 0);
      }
    }
  }
  const int eq = (lane >> 4) * 4;
#pragma unroll
  for (int ni = 0; ni < 4; ++ni) {
    const int col = bn + wn + ni * 16 + fr;
    const float bv = bias[col];
#pragma unroll
    for (int mi = 0; mi < 4; ++mi) {
      const int row0 = bm + wm + mi * 16 + eq;
#pragma unroll
      for (int r = 0; r < 4; ++r) {
        float v = acc[mi][ni][r] + bv;
        if (MODE == 0) {
          ((float*)C0v)[(size_t)(row0 + r) * N + col] = v;
        } else {
          v = gelu_f(v);
          ush h = f2bf(v);
          ush l = f2bf(v - bf2f(h));
          ((ush*)C0v)[(size_t)(row0 + r) * N + col] = h;
          ((ush*)C1v)[(size_t)(row0 + r) * N + col] = l;
        }
      }
    }
  }
}

// ---------------- f32 -> bf16 h/l row split (pooled pre-split) --------------
__global__ __launch_bounds__(256)
void psplit_k(const float* __restrict__ X, ush* __restrict__ H,
              ush* __restrict__ L)
{
  const size_t i = (size_t)blockIdx.x * 1024 + threadIdx.x * 4;
  float4 v = *(const float4*)&X[i];
  ushort4 h, l;
  h.x = f2bf(v.x); l.x = f2bf(v.x - bf2f(h.x));
  h.y = f2bf(v.y); l.y = f2bf(v.y - bf2f(h.y));
  h.z = f2bf(v.z); l.z = f2bf(v.z - bf2f(h.z));
  h.w = f2bf(v.w); l.w = f2bf(v.w - bf2f(h.w));
  *(ushort4*)&H[i] = h;
  *(ushort4*)&L[i] = l;
}

// ---------------- f32 -> bf16 h/m/l split (encoder A pre-split) -------------
__global__ __launch_bounds__(256)
void psplit3_k(const float* __restrict__ X, ush* __restrict__ H,
               ush* __restrict__ M, ush* __restrict__ L)
{
  const size_t i = (size_t)blockIdx.x * 1024 + threadIdx.x * 4;
  float4 v = *(const float4*)&X[i];
  ushort4 h, m, l;
  float r;
  h.x = f2bf(v.x); r = v.x - bf2f(h.x); m.x = f2bf_t(r); l.x = f2bf_t(r - bf2f(m.x));
  h.y = f2bf(v.y); r = v.y - bf2f(h.y); m.y = f2bf_t(r); l.y = f2bf_t(r - bf2f(m.y));
  h.z = f2bf(v.z); r = v.z - bf2f(h.z); m.z = f2bf_t(r); l.z = f2bf_t(r - bf2f(m.z));
  h.w = f2bf(v.w); r = v.w - bf2f(h.w); m.w = f2bf_t(r); l.w = f2bf_t(r - bf2f(m.w));
  *(ushort4*)&H[i] = h;
  *(ushort4*)&M[i] = m;
  *(ushort4*)&L[i] = l;
}

// ---------------- weight transpose + split kernels --------------------------
__global__ __launch_bounds__(256)
void wt_k(const float* __restrict__ W, ush* __restrict__ Th, ush* __restrict__ Tl,
          int K, int N)
{
  __shared__ float tile[32][33];
  const int k0 = blockIdx.y * 32, n0 = blockIdx.x * 32;
  const int tx = threadIdx.x & 31, ty = threadIdx.x >> 5;
#pragma unroll
  for (int j = 0; j < 32; j += 8)
    tile[ty + j][tx] = W[(size_t)(k0 + ty + j) * N + n0 + tx];
  __syncthreads();
#pragma unroll
  for (int j = 0; j < 32; j += 8) {
    float v = tile[tx][ty + j];
    ush h = f2bf(v);
    ush l = f2bf(v - bf2f(h));
    size_t o = (size_t)(n0 + ty + j) * K + k0 + tx;
    Th[o] = h;
    Tl[o] = l;
  }
}

__global__ __launch_bounds__(256)
void wt3_k(const float* __restrict__ W, ush* __restrict__ Th,
           ush* __restrict__ Tm, ush* __restrict__ Tl, int K, int N)
{
  __shared__ float tile[32][33];
  const int k0 = blockIdx.y * 32, n0 = blockIdx.x * 32;
  const int tx = threadIdx.x & 31, ty = threadIdx.x >> 5;
#pragma unroll
  for (int j = 0; j < 32; j += 8)
    tile[ty + j][tx] = W[(size_t)(k0 + ty + j) * N + n0 + tx];
  __syncthreads();
#pragma unroll
  for (int j = 0; j < 32; j += 8) {
    float v = tile[tx][ty + j];
    ush h = f2bf(v);
    float r = v - bf2f(h);
    ush m = f2bf_t(r);
    ush l = f2bf_t(r - bf2f(m));
    size_t o = (size_t)(n0 + ty + j) * K + k0 + tx;
    Th[o] = h;
    Tm[o] = m;
    Tl[o] = l;
  }
}

// ---------------- fused flash attention (bf16x2-split MFMA) -----------------
__device__ __forceinline__ int swz(int r, int c) {
  return (r << 6) + (c ^ ((((r & 7) ^ ((r >> 2) & 7))) << 3));
}
__device__ __forceinline__ int swzv(int d, int kv) {
  return (d << 6) + (kv ^ ((((d & 7) ^ ((d >> 3) & 7))) << 3));
}

__global__ __launch_bounds__(256)
void attn_k(const float* __restrict__ QKV, const float* __restrict__ mask,
            float* __restrict__ O, int mode)
{
  __shared__ __align__(16) ush smem[4 * 4096];
  __shared__ float kb[64];
  ush* QVh = smem;              // Q planes, overlaid by V^T after prologue
  ush* QVl = smem + 4096;
  ush* KPh = smem + 8192;       // K planes, overlaid by P after QK^T
  ush* KPl = smem + 12288;

  const int tid = threadIdx.x;
  const int lane = tid & 63, wave = tid >> 6;
  const int b = blockIdx.x >> 4, h = blockIdx.x & 15;
  const int q0 = blockIdx.y * 64;
  const int lr = tid >> 2;                 // 0..63
  const int lc = (tid & 3) * 16;           // 0,16,32,48
  const int fr = lane & 15;
  const int fq = (lane >> 4) * 8;
  const int hi4 = (lane >> 4) * 4;
  const int wm = wave * 16;

  {
    const float* qp = QKV + (size_t)(b * Ss + q0 + lr) * QKVN + h * HDd + lc;
#pragma unroll
    for (int hf = 0; hf < 2; ++hf) {
      float4 a = *(const float4*)(qp + hf * 8);
      float4 c4 = *(const float4*)(qp + hf * 8 + 4);
      float vals[8] = {a.x, a.y, a.z, a.w, c4.x, c4.y, c4.z, c4.w};
      v8s hv, lv;
#pragma unroll
      for (int j = 0; j < 8; ++j) {
        float v = vals[j] * 0.125f;
        ush hh = f2bf(v);
        ush ll = f2bf(v - bf2f(hh));
        hv[j] = (short)hh; lv[j] = (short)ll;
      }
      int ix = swz(lr, lc + hf * 8);
      *(v8s*)&QVh[ix] = hv;
      *(v8s*)&QVl[ix] = lv;
    }
  }
  __syncthreads();
  v8s qah[2], qal[2];
#pragma unroll
  for (int kh = 0; kh < 2; ++kh) {
    int ix = swz(wm + fr, kh * 32 + fq);
    qah[kh] = *(const v8s*)&QVh[ix];
    qal[kh] = *(const v8s*)&QVl[ix];
  }

  float m_i[4], l_i[4];
  v4f o_acc[4];
#pragma unroll
  for (int i = 0; i < 4; ++i) {
    m_i[i] = -3.0e38f; l_i[i] = 0.f;
    o_acc[i] = (v4f){0.f, 0.f, 0.f, 0.f};
  }

  for (int kt = 0; kt < Ss / 64; ++kt) {
    const int k0 = kt * 64;
    __syncthreads();
    {
      const float* kp = QKV + 1024 + (size_t)(b * Ss + k0 + lr) * QKVN + h * HDd + lc;
      const float* vp = kp + 1024;
#pragma unroll
      for (int hf = 0; hf < 2; ++hf) {
        float4 a = *(const float4*)(kp + hf * 8);
        float4 c4 = *(const float4*)(kp + hf * 8 + 4);
        float vals[8] = {a.x, a.y, a.z, a.w, c4.x, c4.y, c4.z, c4.w};
        v8s hv, lv;
#pragma unroll
        for (int j = 0; j < 8; ++j) {
          float v = vals[j];
          ush hh = f2bf(v);
          ush ll = f2bf(v - bf2f(hh));
          hv[j] = (short)hh; lv[j] = (short)ll;
        }
        int ix = swz(lr, lc + hf * 8);
        *(v8s*)&KPh[ix] = hv;
        *(v8s*)&KPl[ix] = lv;
      }
#pragma unroll
      for (int hf = 0; hf < 2; ++hf) {
        float4 a = *(const float4*)(vp + hf * 8);
        float4 c4 = *(const float4*)(vp + hf * 8 + 4);
        float vals[8] = {a.x, a.y, a.z, a.w, c4.x, c4.y, c4.z, c4.w};
#pragma unroll
        for (int j = 0; j < 8; ++j) {
          float v = vals[j];
          ush hh = f2bf(v);
          ush ll = f2bf(v - bf2f(hh));
          int d = lc + hf * 8 + j;
          int ix = swzv(d, lr);
          QVh[ix] = hh;
          QVl[ix] = ll;
        }
      }
      if (tid < 64) {
        float mv = mask[b * Ss + k0 + tid];
        kb[tid] = mode ? (mv > 0.f ? 0.f : -1.0e9f) : mv;
      }
    }
    __syncthreads();

    v4f sacc[4] = {};
#pragma unroll
    for (int ni = 0; ni < 4; ++ni) {
#pragma unroll
      for (int kh = 0; kh < 2; ++kh) {
        int ix = swz(ni * 16 + fr, kh * 32 + fq);
        v8s bh = *(const v8s*)&KPh[ix];
        v8s bl = *(const v8s*)&KPl[ix];
        sacc[ni] = __builtin_amdgcn_mfma_f32_16x16x32_bf16(qah[kh], bh, sacc[ni], 0, 0, 0);
        sacc[ni] = __builtin_amdgcn_mfma_f32_16x16x32_bf16(qal[kh], bh, sacc[ni], 0, 0, 0);
        sacc[ni] = __builtin_amdgcn_mfma_f32_16x16x32_bf16(qah[kh], bl, sacc[ni], 0, 0, 0);
      }
    }
    __syncthreads();

    float kbv[4];
#pragma unroll
    for (int ni = 0; ni < 4; ++ni) kbv[ni] = kb[ni * 16 + fr];
#pragma unroll
    for (int r = 0; r < 4; ++r) {
      float s0 = sacc[0][r] + kbv[0];
      float s1 = sacc[1][r] + kbv[1];
      float s2 = sacc[2][r] + kbv[2];
      float s3 = sacc[3][r] + kbv[3];
      float mx = fmaxf(fmaxf(s0, s1), fmaxf(s2, s3));
#pragma unroll
      for (int off = 1; off < 16; off <<= 1) mx = fmaxf(mx, __shfl_xor(mx, off, 64));
      float mnew = fmaxf(m_i[r], mx);
      float p0 = expf(s0 - mnew);
      float p1 = expf(s1 - mnew);
      float p2 = expf(s2 - mnew);
      float p3 = expf(s3 - mnew);
      float sum = p0 + p1 + p2 + p3;
#pragma unroll
      for (int off = 1; off < 16; off <<= 1) sum += __shfl_xor(sum, off, 64);
      float alpha = expf(m_i[r] - mnew);
      l_i[r] = l_i[r] * alpha + sum;
      m_i[r] = mnew;
#pragma unroll
      for (int nj = 0; nj < 4; ++nj) o_acc[nj][r] *= alpha;
      const int qrow = wm + hi4 + r;
      float pv[4] = {p0, p1, p2, p3};
#pragma unroll
      for (int ni = 0; ni < 4; ++ni) {
        ush ph = f2bf(pv[ni]);
        ush pl = f2bf(pv[ni] - bf2f(ph));
        int ix = swz(qrow, ni * 16 + fr);
        KPh[ix] = ph;
        KPl[ix] = pl;
      }
    }
    __syncthreads();

#pragma unroll
    for (int kh = 0; kh < 2; ++kh) {
      int aix = swz(wm + fr, kh * 32 + fq);
      v8s pah = *(const v8s*)&KPh[aix];
      v8s pal = *(const v8s*)&KPl[aix];
#pragma unroll
      for (int nj = 0; nj < 4; ++nj) {
        int vix = swzv(nj * 16 + fr, kh * 32 + fq);
        v8s vh = *(const v8s*)&QVh[vix];
        v8s vl = *(const v8s*)&QVl[vix];
        o_acc[nj] = __builtin_amdgcn_mfma_f32_16x16x32_bf16(pah, vh, o_acc[nj], 0, 0, 0);
        o_acc[nj] = __builtin_amdgcn_mfma_f32_16x16x32_bf16(pal, vh, o_acc[nj], 0, 0, 0);
        o_acc[nj] = __builtin_amdgcn_mfma_f32_16x16x32_bf16(pah, vl, o_acc[nj], 0, 0, 0);
      }
    }
  }

#pragma unroll
  for (int r = 0; r < 4; ++r) {
    float inv = 1.0f / l_i[r];
    const size_t row = (size_t)(b * Ss + q0 + wm + hi4 + r);
#pragma unroll
    for (int nj = 0; nj < 4; ++nj)
      O[row * Dd + h * HDd + nj * 16 + fr] = o_acc[nj][r] * inv;
  }
}

// ---------------- fused residual-add + LayerNorm ----------------------------
__global__ __launch_bounds__(256)
void ln_k(const float* __restrict__ X, const float* __restrict__ R,
          const float* __restrict__ g, const float* __restrict__ be,
          float* __restrict__ Out)
{
  __shared__ float red[8];
  const int row = blockIdx.x;
  const int tid = threadIdx.x;
  const int d = tid * 4;
  float4 xv = *(const float4*)(X + (size_t)row * Dd + d);
  float4 rv = *(const float4*)(R + (size_t)row * Dd + d);
  float v0 = xv.x + rv.x, v1 = xv.y + rv.y, v2 = xv.z + rv.z, v3 = xv.w + rv.w;
  float sum = v0 + v1 + v2 + v3;
#pragma unroll
  for (int off = 32; off; off >>= 1) sum += __shfl_xor(sum, off, 64);
  const int wave = tid >> 6, lane = tid & 63;
  if (lane == 0) red[wave] = sum;
  __syncthreads();
  float mean = (red[0] + red[1] + red[2] + red[3]) * (1.0f / Dd);
  float d0 = v0 - mean, d1 = v1 - mean, d2 = v2 - mean, d3 = v3 - mean;
  float ss = d0 * d0 + d1 * d1 + d2 * d2 + d3 * d3;
#pragma unroll
  for (int off = 32; off; off >>= 1) ss += __shfl_xor(ss, off, 64);
  if (lane == 0) red[4 + wave] = ss;
  __syncthreads();
  float var = (red[4] + red[5] + red[6] + red[7]) * (1.0f / Dd);
  float inv = 1.0f / sqrtf(var + 1e-5f);
  float4 gv = *(const float4*)(g + d);
  float4 bv = *(const float4*)(be + d);
  float4 r;
  r.x = d0 * inv * gv.x + bv.x;
  r.y = d1 * inv * gv.y + bv.y;
  r.z = d2 * inv * gv.z + bv.z;
  r.w = d3 * inv * gv.w + bv.w;
  *(float4*)&Out[(size_t)row * Dd + d] = r;
}

// ---------------- per-token sigmoid score -----------------------------------
__global__ __launch_bounds__(256)
void score_k(const float* __restrict__ F, const float* __restrict__ Wsv,
             const float* __restrict__ bs, float* __restrict__ Sout)
{
  const int tok = blockIdx.x * 4 + (threadIdx.x >> 6);
  const int lane = threadIdx.x & 63;
  const float* fp = F + (size_t)tok * Dd;
  float acc = 0.f;
#pragma unroll
  for (int ii = 0; ii < 16; ++ii) {
    int d = lane + ii * 64;
    acc += fp[d] * Wsv[d];
  }
#pragma unroll
  for (int off = 32; off; off >>= 1) acc += __shfl_xor(acc, off, 64);
  if (lane == 0) Sout[tok] = 1.0f / (1.0f + expf(-(acc + bs[0])));
}

// ---------------- per-batch scan: sv, seg, new_mask, nact -------------------
__global__ __launch_bounds__(256)
void scan_k(const float* __restrict__ sin, const float* __restrict__ mask,
            float* __restrict__ svout, int* __restrict__ segout,
            float* __restrict__ nmask, int* __restrict__ nact)
{
  __shared__ double sc[256];
  __shared__ float mxs[256];
  const int b = blockIdx.x;
  const int tid = threadIdx.x;
  const int t0 = tid * 4;
  float svl[4], mk[4];
  double loc[4];
  double run = 0.0;
#pragma unroll
  for (int i = 0; i < 4; i++) {
    float s = sin[b * Ss + t0 + i];
    float m = mask[b * Ss + t0 + i];
    float sv = (m > 0.f) ? s : 0.f;
    svl[i] = sv; mk[i] = m;
    run += (double)sv;
    loc[i] = run;
  }
  sc[tid] = run;
  __syncthreads();
  for (int off = 1; off < 256; off <<= 1) {
    double add = (tid >= off) ? sc[tid - off] : 0.0;
    __syncthreads();
    sc[tid] += add;
    __syncthreads();
  }
  double excl = sc[tid] - run;
  float lmax = -1.0f;
#pragma unroll
  for (int i = 0; i < 4; i++) {
    double c = floor(excl + loc[i]);
    int sg = (int)c;
    if (sg < 0) sg = 0;
    if (sg > Ss - 1) sg = Ss - 1;
    svout[b * Ss + t0 + i] = svl[i];
    segout[b * Ss + t0 + i] = sg;
    if (mk[i] > 0.f) lmax = fmaxf(lmax, (float)c);
  }
  mxs[tid] = lmax;
  __syncthreads();
  for (int off = 128; off; off >>= 1) {
    if (tid < off) mxs[tid] = fmaxf(mxs[tid], mxs[tid + off]);
    __syncthreads();
  }
  float mseg = mxs[0];
  if (tid == 0) {
    int na = (int)mseg + 1;
    if (na < 1) na = 1;
    if (na > Ss) na = Ss;
    nact[b] = na;
  }
#pragma unroll
  for (int i = 0; i < 4; i++)
    nmask[b * Ss + t0 + i] = ((float)(t0 + i) <= mseg) ? 1.0f : 0.0f;
}

// ---------------- weighted segment scatter-add ------------------------------
__global__ __launch_bounds__(256)
void scatter_k(const float* __restrict__ X, const float* __restrict__ sv,
               const int* __restrict__ seg, float* __restrict__ pooled)
{
  const int tok = blockIdx.x;
  const float w = sv[tok];
  if (w == 0.f) return;
  const int b = tok >> 10;
  const int sg = seg[tok];
  const int d = threadIdx.x * 4;
  float4 xv = *(const float4*)(X + (size_t)tok * Dd + d);
  float* pp = pooled + ((size_t)(b * Ss + sg)) * Dd + d;
  atomicAdd(pp + 0, xv.x * w);
  atomicAdd(pp + 1, xv.y * w);
  atomicAdd(pp + 2, xv.z * w);
  atomicAdd(pp + 3, xv.w * w);
}

// ---------------- small helpers: bias concat, const rows --------------------
__global__ __launch_bounds__(256)
void bcat_k(const float* __restrict__ bq, const float* __restrict__ bk,
            const float* __restrict__ bv, float* __restrict__ out)
{
  int i = blockIdx.x * 256 + threadIdx.x;     // 3072 total
  float v = (i < 1024) ? bq[i] : (i < 2048) ? bk[i - 1024] : bv[i - 2048];
  out[i] = v;
}
__global__ __launch_bounds__(256)
void cv1_k(const float* __restrict__ bp1, float* __restrict__ cv1)
{
  int i = blockIdx.x * 256 + threadIdx.x;     // 4096
  cv1[i] = gelu_f(bp1[i]);
}
// cv2[col] = sum_k cv1[k]*(P2T_h+P2T_l)[col][k] + bp2[col]; 4 cols/block
__global__ __launch_bounds__(256)
void cv2_k(const float* __restrict__ cv1, const ush* __restrict__ p2h,
           const ush* __restrict__ p2l, const float* __restrict__ bp2,
           float* __restrict__ cv2)
{
  const int col = blockIdx.x * 4 + (threadIdx.x >> 6);
  const int lane = threadIdx.x & 63;
  const ush* rh = p2h + (size_t)col * HIDh;
  const ush* rl = p2l + (size_t)col * HIDh;
  float acc = 0.f;
#pragma unroll
  for (int ii = 0; ii < 64; ++ii) {
    int k = lane + ii * 64;
    acc += cv1[k] * (bf2f(rh[k]) + bf2f(rl[k]));
  }
#pragma unroll
  for (int off = 32; off; off >>= 1) acc += __shfl_xor(acc, off, 64);
  if (lane == 0) cv2[col] = acc + bp2[col];
}

static inline void launch_gemm6(const float* A, const ush* Bh, const ush* Bm,
                                const ush* Bl, const float* bias, float* C,
                                int M, int N, int K, bool gelu, int bn,
                                hipStream_t st)
{
  dim3 blk(256);
  if (bn == 128) {
    dim3 g(N / 128, M / 128);
    if (gelu) hipLaunchKernelGGL((gemm6_k<1,128>), g, blk, 0, st, A, Bh, Bm, Bl, bias, C, M, N, K);
    else      hipLaunchKernelGGL((gemm6_k<0,128>), g, blk, 0, st, A, Bh, Bm, Bl, bias, C, M, N, K);
  } else {
    dim3 g(N / 64, M / 128);
    if (gelu) hipLaunchKernelGGL((gemm6_k<1,64>), g, blk, 0, st, A, Bh, Bm, Bl, bias, C, M, N, K);
    else      hipLaunchKernelGGL((gemm6_k<0,64>), g, blk, 0, st, A, Bh, Bm, Bl, bias, C, M, N, K);
  }
}

extern "C" void kernel_launch(void* const* d_in, const int* in_sizes, int n_in,
                              void* d_out, int out_size, void* d_ws, size_t ws_size,
                              hipStream_t stream)
{
  const float* x     = (const float*)d_in[0];
  const float* masks = (const float*)d_in[1];
  const float* Wq  = (const float*)d_in[2];
  const float* bq  = (const float*)d_in[3];
  const float* Wk  = (const float*)d_in[4];
  const float* bk  = (const float*)d_in[5];
  const float* Wv  = (const float*)d_in[6];
  const float* bv  = (const float*)d_in[7];
  const float* Wo  = (const float*)d_in[8];
  const float* bo  = (const float*)d_in[9];
  const float* g1  = (const float*)d_in[10];
  const float* be1 = (const float*)d_in[11];
  const float* g2  = (const float*)d_in[12];
  const float* be2 = (const float*)d_in[13];
  const float* W1  = (const float*)d_in[14];
  const float* bf1 = (const float*)d_in[15];
  const float* W2  = (const float*)d_in[16];
  const float* bf2 = (const float*)d_in[17];
  const float* Wsp = (const float*)d_in[18];
  const float* bs  = (const float*)d_in[19];
  const float* P1  = (const float*)d_in[20];
  const float* bp1 = (const float*)d_in[21];
  const float* P2  = (const float*)d_in[22];
  const float* bp2 = (const float*)d_in[23];

  // ---- workspace: [W3 24M ush = 48MB][u0..u5 6x16.78MB][smalls] ≈ 148.9MB
  const size_t UW = (size_t)Dd * Dd;        // 1,048,576
  const size_t ND = (size_t)NTOK * Dd;      // 4,194,304 floats
  ush* w3 = (ush*)d_ws;
  ush *wqkvh = w3 + 0*UW, *wqkvm = w3 + 3*UW, *wqkvl = w3 + 6*UW;
  ush *woh = w3 + 9*UW,  *wom = w3 + 10*UW, *wol = w3 + 11*UW;
  ush *w1h = w3 + 12*UW, *w1m = w3 + 14*UW, *w1l = w3 + 16*UW;
  ush *w2h = w3 + 18*UW, *w2m = w3 + 20*UW, *w2l = w3 + 22*UW;
  float* ub = (float*)(w3 + 24*UW);
  float* u0 = ub + 0 * ND;
  float* u1 = ub + 1 * ND;
  float* u2 = ub + 2 * ND;
  float* u3 = ub + 3 * ND;
  float* u4 = ub + 4 * ND;
  float* u5 = ub + 5 * ND;
  float* sm = ub + 6 * ND;
  float* sbuf = sm;                  // NTOK
  float* svb  = sm + NTOK;           // NTOK
  int*   segb = (int*)(sm + 2 * NTOK);
  int*   nact = (int*)(sm + 3 * NTOK);           // 4 ints
  float* bqkv = sm + 3 * NTOK + 16;              // 3072
  float* cv1  = bqkv + QKVN;                     // 4096
  float* cv2  = cv1 + HIDh;                      // 4096

  float* pooled = u0;
  ush*   pooled_h = (ush*)u1;                    // 4M ush = 8MB
  ush*   pooled_l = pooled_h + ND;               // 4M ush
  ush*   hid_h = (ush*)u2;                       // 16M ush (spans u2+u3)
  ush*   hid_l = (ush*)u4;                       // 16M ush (spans u4+u5)
  ush*   p1h = w3;                   // 4M ush
  ush*   p1l = w3 + 4*UW;
  ush*   p2h = (ush*)d_ws;           // 16M ush each plane
  ush*   p2l = p2h + (size_t)HIDh * HIDh;
  float* outp = (float*)d_out;
  float* nmask = outp + (size_t)NTOK * HIDh;

  // xin-split planes (4M ush each) in dead workspace slices:
  // pass1: u3 + first half of u4 (ao=u3 / t1=u4 written only after QKV reads)
  // pass2: u0 + first half of u1 (ao=u0 / t1=u1 written only after QKV reads)
  ush* xs1h = (ush*)u3; ush* xs1m = xs1h + ND; ush* xs1l = xs1h + 2*ND;
  ush* xs2h = (ush*)u0; ush* xs2m = xs2h + ND; ush* xs2l = xs2h + 2*ND;

  // ---- weight prep ---------------------------------------------------------
  hipLaunchKernelGGL(wt3_k, dim3(Dd/32, Dd/32), dim3(256), 0, stream, Wq, wqkvh,        wqkvm,        wqkvl,        Dd, Dd);
  hipLaunchKernelGGL(wt3_k, dim3(Dd/32, Dd/32), dim3(256), 0, stream, Wk, wqkvh + UW,   wqkvm + UW,   wqkvl + UW,   Dd, Dd);
  hipLaunchKernelGGL(wt3_k, dim3(Dd/32, Dd/32), dim3(256), 0, stream, Wv, wqkvh + 2*UW, wqkvm + 2*UW, wqkvl + 2*UW, Dd, Dd);
  hipLaunchKernelGGL(wt3_k, dim3(Dd/32, Dd/32), dim3(256), 0, stream, Wo, woh, wom, wol, Dd, Dd);
  hipLaunchKernelGGL(wt3_k, dim3(FFf/32, Dd/32), dim3(256), 0, stream, W1, w1h, w1m, w1l, Dd, FFf);
  hipLaunchKernelGGL(wt3_k, dim3(Dd/32, FFf/32), dim3(256), 0, stream, W2, w2h, w2m, w2l, FFf, Dd);
  hipLaunchKernelGGL(bcat_k, dim3(QKVN/256), dim3(256), 0, stream, bq, bk, bv, bqkv);
  hipLaunchKernelGGL(cv1_k, dim3(HIDh/256), dim3(256), 0, stream, bp1, cv1);

  auto enc = [&](const float* xin, ush* xsh, ush* xsm, ush* xsl,
                 float* qkv, float* ao, float* t1, float* hb,
                 float* ffh, float* t1b, float* fout, int mode) {
    hipLaunchKernelGGL(psplit3_k, dim3(NTOK), dim3(256), 0, stream, xin, xsh, xsm, xsl);
    hipLaunchKernelGGL(gemm6p_k, dim3(QKVN / 128, NTOK / 128), dim3(256), 0, stream,
                       xsh, xsm, xsl, wqkvh, wqkvm, wqkvl, bqkv, qkv, NTOK, QKVN, Dd);
    hipLaunchKernelGGL(attn_k, dim3(Bb * Hh, Ss / 64), dim3(256), 0, stream,
                       qkv, masks, ao, mode);
    launch_gemm6(ao, woh, wom, wol, bo, t1, NTOK, Dd, Dd, false, 64, stream);
    hipLaunchKernelGGL(ln_k, dim3(NTOK), dim3(256), 0, stream, t1, xin, g1, be1, hb);
    launch_gemm6(hb, w1h, w1m, w1l, bf1, ffh, NTOK, FFf, Dd, true, 128, stream);
    launch_gemm6(ffh, w2h, w2m, w2l, bf2, t1b, NTOK, Dd, FFf, false, 64, stream);
    hipLaunchKernelGGL(ln_k, dim3(NTOK), dim3(256), 0, stream, t1b, hb, g2, be2, fout);
  };

  // pass 1 (float mask ADDED): xin=x, xsplit in u3/u4-half (dead before ao/t1)
  enc(x,  xs1h, xs1m, xs1l, u0, u3, u4, u5, u0 /*ffh=u0u1*/, u4, u2 /*feat1*/, 0);
  // pass 2 (0/-1e9 mask): xin=u2, xsplit in u0/u1-half (dead before ao/t1)
  enc(u2, xs2h, xs2m, xs2l, u3, u0, u1, u3, u4 /*ffh=u4u5*/, u0, u1 /*feat2*/, 1);

  hipLaunchKernelGGL(score_k, dim3(NTOK / 4), dim3(256), 0, stream, u1, Wsp, bs, sbuf);
  hipLaunchKernelGGL(scan_k, dim3(Bb), dim3(256), 0, stream, sbuf, masks, svb, segb, nmask, nact);
  hipMemsetAsync(pooled, 0, ND * sizeof(float), stream);
  hipLaunchKernelGGL(scatter_k, dim3(NTOK), dim3(256), 0, stream, x, svb, segb, pooled);

  // projector: pre-split A planes, all-DMA, R4-proven 128x128 dbuf + skip
  hipLaunchKernelGGL(psplit_k, dim3(NTOK), dim3(256), 0, stream, pooled, pooled_h, pooled_l);
  hipLaunchKernelGGL(wt_k, dim3(HIDh / 32, Dd / 32), dim3(256), 0, stream, P1, p1h, p1l, Dd, HIDh);
  hipLaunchKernelGGL((gemm3p_k<1>), dim3(HIDh / 128, NTOK / 128), dim3(256), 0, stream,
                     pooled_h, pooled_l, p1h, p1l, bp1, (void*)hid_h, (void*)hid_l,
                     NTOK, HIDh, Dd, nact, cv1);
  hipLaunchKernelGGL(wt_k, dim3(HIDh / 32, HIDh / 32), dim3(256), 0, stream, P2, p2h, p2l, HIDh, HIDh);
  hipLaunchKernelGGL(cv2_k, dim3(HIDh / 4), dim3(256), 0, stream, cv1, p2h, p2l, bp2, cv2);
  hipLaunchKernelGGL((gemm3p_k<0>), dim3(HIDh / 128, NTOK / 128), dim3(256), 0, stream,
                     hid_h, hid_l, p2h, p2l, bp2, (void*)outp, nullptr,
                     NTOK, HIDh, HIDh, nact, cv2);
}